// Round 10
// baseline (247.998 us; speedup 1.0000x reference)
//
#include <hip/hip_runtime.h>

// Problem: 3x3 VALID conv, NCHW fp32.
// data: [16, 64, 128, 128], weights: [128, 64, 3, 3] -> out [16, 128, 126, 126]
// R9 = R8 + the missing `s_waitcnt lgkmcnt(0)` BEFORE each raw s_barrier.
// R8's race: s_barrier does NOT drain counters (ISA §8: "s_waitcnt first if
// data dep!") -- a wave could pass barrier t with tap t-1 ds_reads still in
// flight while another wave's tap t+2 DMA rewrote that same buffer. The
// lgkmcnt(0) pre-drain bounds skew correctly and costs ~nothing (the MFMAs
// already consumed those reads). The expensive per-tap vmcnt(0) drain of the
// just-issued A-DMA (R7's __syncthreads) stays REMOVED: counted vmcnt(8/4/0)
// with triple-buffered, wave-OWNED A chunks (twin waves duplicate-write
// identical bytes -- benign).

#define BATCH 16
#define CIN   64
#define HIN   128
#define WIN   128
#define COUT  128
#define HO    126
#define WO    126

typedef short bf16x8 __attribute__((ext_vector_type(8)));
typedef float f32x4  __attribute__((ext_vector_type(4)));

__device__ __forceinline__ unsigned short f2bf(float f) {
    union { float f; unsigned int u; } v; v.f = f;
    unsigned int u = v.u;
    unsigned int r = (u + 0x7fffu + ((u >> 16) & 1u)) >> 16;
    return (unsigned short)r;
}

// async global->LDS, 16B per lane. LDS dest = wave-uniform base + lane*16.
__device__ __forceinline__ void async16(const void* g, void* l) {
    __builtin_amdgcn_global_load_lds(
        (const __attribute__((address_space(1))) unsigned int*)(unsigned long long)g,
        (__attribute__((address_space(3))) unsigned int*)(unsigned long long)l,
        16, 0, 0);
}

// ---------- Pre-pass: weights [co][ci][kh][kw] fp32 -> [kh*3+kw][co][ci] bf16 ----------
__global__ __launch_bounds__(256) void t2_weights(
        const float* __restrict__ w, unsigned short* __restrict__ wt) {
    const int idx = blockIdx.x * 256 + threadIdx.x;
    if (idx < COUT * CIN * 9) {
        const int co = idx / (CIN * 9);
        const int r  = idx % (CIN * 9);
        const int ci = r / 9;
        const int k  = r % 9;
        wt[((size_t)k * COUT + co) * CIN + ci] = f2bf(w[idx]);
    }
}

// ---------- Fused: register-gather transpose + counted-vmcnt MFMA K-loop ----------
// grid (2 wtiles, 126 oh, 16 b) = 4032 blocks; block 512 = 8 waves.
// Wave tile: 32co x 32sp. Block: 128co x 63/64ow x 1oh.
__global__ __launch_bounds__(512, 4) void conv_fused(
        const float* __restrict__ x,               // [b][ci][h][w] fp32
        const unsigned short* __restrict__ wt,     // [tap][co][ci] bf16
        float* __restrict__ out) {
    // LDS: halo [3*68 rows][64 ci] bf16, swizzled (26,112 B)
    //      + A triple-buffer 3 x [128 co][64 ci] swizzled (49,152 B).
    __shared__ __align__(16) char smem[26112 + 49152];
    short* halo = (short*)smem;
    short* As   = (short*)(smem + 26112);

    // XCD chunking: nwg=4032=8*504 (bijective); XCD k gets 2 full batches.
    const int raw = (blockIdx.z * 126 + blockIdx.y) * 2 + blockIdx.x;
    const int s = (raw & 7) * 504 + (raw >> 3);
    const int b  = s / 252;
    const int r2 = s - b * 252;
    const int oh = r2 >> 1;
    const int W0 = (r2 & 1) * 64;   // ow tile base

    const int tid  = threadIdx.x;
    const int lane = tid & 63, wid = tid >> 6;   // wid 0..7
    const int co0  = (wid & 3) * 32;
    const int n0   = (wid >> 2) * 32;
    const int col  = lane & 15, quad = lane >> 4;
    // global_load_lds source pre-swizzle per 1KB-aligned chunk:
    // LDS linear byte L holds global byte L ^ ((row&7)<<4), rows 128 B.
    const int swl = (lane * 16) ^ ((lane >> 3) << 4);
    // Wave-OWNED A chunks: exactly the co-slice this wave's ds_reads touch
    // (rows co0..co0+31 = bytes co0*128..+4096 = chunks (wid&3)*4 .. +3).
    const int cbase = (wid & 3) * 4;

    // ---- Transpose loads: register gather, single latency exposure. ----
    const int tw = tid & 63, oct = tid >> 6;
    float v[3][8];
    {
        const float* xb = x + ((size_t)b * CIN + oct * 8) * (HIN * WIN)
                            + (size_t)oh * WIN + W0 + tw;
#pragma unroll
        for (int kh = 0; kh < 3; kh++)
#pragma unroll
            for (int j = 0; j < 8; j++)
                v[kh][j] = xb[(size_t)j * (HIN * WIN) + kh * WIN];
    }
    // Tail rows w=64..67 (96 tasks). Valid & needed only for W0==0; for
    // W0==64 clamp to w=127 (garbage feeds only ow>=126 lanes, never stored).
    float tv[8];
    const int oct2 = tid & 7, tw2 = 64 + ((tid >> 3) & 3), tkh = tid >> 5;
    if (tid < 96) {
        int wi = W0 + tw2; if (wi > WIN - 1) wi = WIN - 1;
        const float* xb2 = x + ((size_t)b * CIN + oct2 * 8) * (HIN * WIN)
                             + (size_t)(oh + tkh) * WIN + wi;
#pragma unroll
        for (int j = 0; j < 8; j++)
            tv[j] = xb2[(size_t)j * (HIN * WIN)];
    }

    // ---- Issue A DMAs for taps 0 and 1 (wave-owned chunks; twin waves
    // duplicate-write identical bytes). Drained by the prologue barrier. ----
#pragma unroll
    for (int tt = 0; tt < 2; tt++) {
        const char* srcA = (const char*)wt + (size_t)tt * 16384;
        char* dstA = (char*)As + tt * 16384;
#pragma unroll
        for (int i = 0; i < 4; i++) {
            const int c = cbase + i;
            async16(srcA + c * 1024 + swl, dstA + c * 1024 + lane * 16);
        }
    }

    // ---- Pack + one swizzled ds_write_b128 per halo row. ----
#pragma unroll
    for (int kh = 0; kh < 3; kh++) {
        bf16x8 p;
#pragma unroll
        for (int j = 0; j < 8; j++) p[j] = (short)f2bf(v[kh][j]);
        const int r = kh * 68 + tw;
        *(bf16x8*)((char*)halo + ((r * 128 + oct * 16) ^ ((r & 7) << 4))) = p;
    }
    if (tid < 96) {
        bf16x8 p;
#pragma unroll
        for (int j = 0; j < 8; j++) p[j] = (short)f2bf(tv[j]);
        const int r = tkh * 68 + tw2;
        *(bf16x8*)((char*)halo + ((r * 128 + oct2 * 16) ^ ((r & 7) << 4))) = p;
    }

    __syncthreads(); // full drain: halo + A taps 0,1 resident; vmcnt clean

    f32x4 acc[2][2] = {};

    // ---- K-loop: 9 taps, A triple-buffered 2 ahead. Per tap:
    // lgkmcnt(0) drain (my LDS reads done) -> raw s_barrier (all waves') ->
    // issue tap t+2 DMA -> counted vmcnt (taps t+1,t+2 stay in flight) ->
    // ds_read + MFMA. No mid-loop vmcnt(0).
#pragma unroll
    for (int t = 0; t < 9; t++) {
        const int kh = t / 3, kw = t - kh * 3;

        if (t) {
            asm volatile("s_waitcnt lgkmcnt(0)" ::: "memory"); // ISA §8 rule
            __builtin_amdgcn_s_barrier();
        }

        if (t + 2 < 9) { // issue tap t+2 into buf (t+2)%3 (owned chunks)
            const char* srcA = (const char*)wt + (size_t)(t + 2) * 16384;
            char* dstA = (char*)As + ((t + 2) % 3) * 16384;
#pragma unroll
            for (int i = 0; i < 4; i++) {
                const int c = cbase + i;
                async16(srcA + c * 1024 + swl, dstA + c * 1024 + lane * 16);
            }
        }

        // Counted wait: drain MY tap-t loads; keep taps t+1,t+2 in flight.
        if (t <= 6)      asm volatile("s_waitcnt vmcnt(8)" ::: "memory");
        else if (t == 7) asm volatile("s_waitcnt vmcnt(4)" ::: "memory");
        else             asm volatile("s_waitcnt vmcnt(0)" ::: "memory");
        __builtin_amdgcn_sched_barrier(0);

        const short* At = As + (t % 3) * 8192; // shorts
#pragma unroll
        for (int kk = 0; kk < 2; kk++) {
            bf16x8 aa[2], bb[2];
#pragma unroll
            for (int mi = 0; mi < 2; mi++) {
                const int r = co0 + mi * 16 + col;
                aa[mi] = *(const bf16x8*)&At[(r * 64 + kk * 32 + quad * 8) ^ ((r & 7) << 3)];
            }
#pragma unroll
            for (int ni = 0; ni < 2; ni++) {
                const int r = kh * 68 + n0 + ni * 16 + col + kw;
                bb[ni] = *(const bf16x8*)&halo[(r * 64 + kk * 32 + quad * 8) ^ ((r & 7) << 3)];
            }
#pragma unroll
            for (int mi = 0; mi < 2; mi++)
#pragma unroll
                for (int ni = 0; ni < 2; ni++)
                    acc[mi][ni] = __builtin_amdgcn_mfma_f32_16x16x32_bf16(
                        aa[mi], bb[ni], acc[mi][ni], 0, 0, 0);
        }
    }

    // ---- Epilogue: direct stores (proven time-neutral pattern). ----
    // C/D layout: col(N=spatial)=lane&15, row(M=co)=quad*4+reg.
#pragma unroll
    for (int ni = 0; ni < 2; ni++) {
        const int ow = W0 + n0 + ni * 16 + col;
        if (ow < WO) {
#pragma unroll
            for (int mi = 0; mi < 2; mi++) {
                const int co = co0 + mi * 16 + quad * 4;
                float* o = out + (((size_t)b * COUT + co) * HO + oh) * WO + ow;
#pragma unroll
                for (int r = 0; r < 4; r++)
                    o[(size_t)r * HO * WO] = acc[mi][ni][r];
            }
        }
    }
}

// ---------- Fallback: direct fp32 conv (if d_ws too small) ----------
__global__ __launch_bounds__(256) void conv_direct(
        const float* __restrict__ x, const float* __restrict__ w,
        float* __restrict__ y) {
    const int idx = blockIdx.x * 256 + threadIdx.x;
    if (idx >= BATCH * COUT * HO * WO) return;
    const int ow = idx % WO;
    int t = idx / WO;
    const int oh = t % HO; t /= HO;
    const int co = t % COUT;
    const int b  = t / COUT;
    float acc = 0.f;
    const float* xb = x + (((size_t)b * CIN) * HIN + oh) * WIN + ow;
    const float* wc = w + (size_t)co * (CIN * 9);
    for (int ci = 0; ci < CIN; ci++) {
#pragma unroll
        for (int kh = 0; kh < 3; kh++)
#pragma unroll
            for (int kw = 0; kw < 3; kw++)
                acc += xb[(size_t)ci * (HIN * WIN) + kh * WIN + kw] * wc[ci * 9 + kh * 3 + kw];
    }
    y[idx] = acc;
}

extern "C" void kernel_launch(void* const* d_in, const int* in_sizes, int n_in,
                              void* d_out, int out_size, void* d_ws, size_t ws_size,
                              hipStream_t stream) {
    const float* data    = (const float*)d_in[0];
    const float* weights = (const float*)d_in[1];
    float* out = (float*)d_out;

    const size_t wt_bytes = (size_t)9 * COUT * CIN * 2; // 144 KiB

    if (ws_size >= wt_bytes) {
        unsigned short* wt = (unsigned short*)d_ws;
        t2_weights<<<(COUT * CIN * 9 + 255) / 256, 256, 0, stream>>>(weights, wt);
        conv_fused<<<dim3(2, 126, BATCH), 512, 0, stream>>>(data, wt, out);
    } else {
        const int n = BATCH * COUT * HO * WO;
        conv_direct<<<(n + 255) / 256, 256, 0, stream>>>(data, weights, out);
    }
}

// Round 11
// 212.108 us; speedup vs baseline: 1.1692x; 1.1692x over previous
//
#include <hip/hip_runtime.h>

// Problem: 3x3 VALID conv, NCHW fp32.
// data: [16, 64, 128, 128], weights: [128, 64, 3, 3] -> out [16, 128, 126, 126]
// R10 = R7's proven sync template (per-tap __syncthreads, A dbuf 1-ahead,
// both-sides swizzle) with 2x-reuse geometry. R9's counted-vmcnt REVERTED
// (it regressed 107->123: sched pinning + twin-duplicated DMA writes).
// Evidence: LDS pipe is the dominant serial resource (~45us of the 107us:
// 576 ds_read_b128/block = 1 read per MFMA at 32x32 wave tiles). Fix:
// wave tile 64co x 32sp + 2-oh block tile (128co x 2oh x 64ow):
//  - ds_reads/MFMA 1.0 -> 0.75; per-output LDS reads x0.75, everything
//    else per-output (transpose px, f2bf VALU, DMA writes, barriers) x0.5.
//  - LDS: halo 4rows x 68w x 64ci bf16 (34,816 B) + A dbuf 32 KB = 67,584 B
//    -> 2 blocks/CU, 4 waves/SIMD (unchanged occupancy).

#define BATCH 16
#define CIN   64
#define HIN   128
#define WIN   128
#define COUT  128
#define HO    126
#define WO    126

typedef short bf16x8 __attribute__((ext_vector_type(8)));
typedef float f32x4  __attribute__((ext_vector_type(4)));

__device__ __forceinline__ unsigned short f2bf(float f) {
    union { float f; unsigned int u; } v; v.f = f;
    unsigned int u = v.u;
    unsigned int r = (u + 0x7fffu + ((u >> 16) & 1u)) >> 16;
    return (unsigned short)r;
}

// async global->LDS, 16B per lane. LDS dest = wave-uniform base + lane*16.
__device__ __forceinline__ void async16(const void* g, void* l) {
    __builtin_amdgcn_global_load_lds(
        (const __attribute__((address_space(1))) unsigned int*)(unsigned long long)g,
        (__attribute__((address_space(3))) unsigned int*)(unsigned long long)l,
        16, 0, 0);
}

// ---------- Pre-pass: weights [co][ci][kh][kw] fp32 -> [kh*3+kw][co][ci] bf16 ----------
__global__ __launch_bounds__(256) void t2_weights(
        const float* __restrict__ w, unsigned short* __restrict__ wt) {
    const int idx = blockIdx.x * 256 + threadIdx.x;
    if (idx < COUT * CIN * 9) {
        const int co = idx / (CIN * 9);
        const int r  = idx % (CIN * 9);
        const int ci = r / 9;
        const int k  = r % 9;
        wt[((size_t)k * COUT + co) * CIN + ci] = f2bf(w[idx]);
    }
}

// ---------- Fused conv: 2-oh block, 64co x 32sp wave tiles ----------
// grid (2 wtiles, 63 oh-pairs, 16 b) = 2016 blocks; block 512 = 8 waves.
// wid&1 -> co half (64); (wid>>1)&3 -> sp group: oh' = s>>1, ow0 = (s&1)*32.
__global__ __launch_bounds__(512, 4) void conv_fused(
        const float* __restrict__ x,               // [b][ci][h][w] fp32
        const unsigned short* __restrict__ wt,     // [tap][co][ci] bf16
        float* __restrict__ out) {
    // LDS: halo [4 rows * 68 w][64 ci] bf16, swizzled (34,816 B)
    //      + A double-buffer 2 x [128 co][64 ci] swizzled (32,768 B).
    __shared__ __align__(16) char smem[34816 + 32768];
    short* halo = (short*)smem;
    short* As   = (short*)(smem + 34816);

    // XCD chunking: nwg=2016=8*252 (bijective); XCD k gets 2 full batches.
    const int raw = (blockIdx.z * 63 + blockIdx.y) * 2 + blockIdx.x;
    const int s = (raw & 7) * 252 + (raw >> 3);
    const int b   = s / 126;
    const int r2  = s - b * 126;
    const int ohp = r2 >> 1;            // oh pair index 0..62
    const int oh0 = ohp * 2;            // output rows oh0, oh0+1
    const int W0  = (r2 & 1) * 64;      // ow tile base

    const int tid  = threadIdx.x;
    const int lane = tid & 63, wid = tid >> 6;   // wid 0..7
    const int co0  = (wid & 1) * 64;
    const int sg   = (wid >> 1) & 3;             // sp group
    const int ohq  = sg >> 1;                    // oh' 0..1
    const int ow0  = (sg & 1) * 32;              // ow sub-base
    const int col  = lane & 15, quad = lane >> 4;
    // global_load_lds source pre-swizzle per 1KB-aligned chunk:
    // LDS linear byte L holds global byte L ^ ((row&7)<<4), rows 128 B.
    const int swl = (lane * 16) ^ ((lane >> 3) << 4);

    // ---- Transpose loads: 4 input rows (oh0..oh0+3, always <=127),
    // register gather, single latency exposure. ----
    const int tw = tid & 63, oct = tid >> 6;
    float v[4][8];
    {
        const float* xb = x + ((size_t)b * CIN + oct * 8) * (HIN * WIN)
                            + (size_t)oh0 * WIN + W0 + tw;
#pragma unroll
        for (int hr = 0; hr < 4; hr++)
#pragma unroll
            for (int j = 0; j < 8; j++)
                v[hr][j] = xb[(size_t)j * (HIN * WIN) + hr * WIN];
    }
    // Tail w=64..67 (128 tasks: 4w x 8oct x 4rows). For W0==64, iw 128..131
    // clamp to 127: garbage feeds only ow'>=62 -> ow>=126 lanes, never stored.
    float tv[8];
    const int tw2 = 64 + (tid & 3), oct2 = (tid >> 2) & 7, hr2 = tid >> 5;
    if (tid < 128) {
        int wi = W0 + tw2; if (wi > WIN - 1) wi = WIN - 1;
        const float* xb2 = x + ((size_t)b * CIN + oct2 * 8) * (HIN * WIN)
                             + (size_t)(oh0 + hr2) * WIN + wi;
#pragma unroll
        for (int j = 0; j < 8; j++)
            tv[j] = xb2[(size_t)j * (HIN * WIN)];
    }

    // ---- Issue A tap-0 DMA (16 chunks / 8 waves = 2 each, each chunk
    // written once). Drained by the prologue barrier. ----
    {
        const char* srcA = (const char*)wt;
        char* dstA = (char*)As;
#pragma unroll
        for (int i = 0; i < 2; i++) {
            const int c = wid * 2 + i;
            async16(srcA + c * 1024 + swl, dstA + c * 1024 + lane * 16);
        }
    }

    // ---- Pack + one swizzled ds_write_b128 per halo row. ----
#pragma unroll
    for (int hr = 0; hr < 4; hr++) {
        bf16x8 p;
#pragma unroll
        for (int j = 0; j < 8; j++) p[j] = (short)f2bf(v[hr][j]);
        const int r = hr * 68 + tw;
        *(bf16x8*)((char*)halo + ((r * 128 + oct * 16) ^ ((r & 7) << 4))) = p;
    }
    if (tid < 128) {
        bf16x8 p;
#pragma unroll
        for (int j = 0; j < 8; j++) p[j] = (short)f2bf(tv[j]);
        const int r = hr2 * 68 + tw2;
        *(bf16x8*)((char*)halo + ((r * 128 + oct2 * 16) ^ ((r & 7) << 4))) = p;
    }

    __syncthreads(); // full drain: halo + A tap 0 resident

    f32x4 acc[4][2] = {};

    // ---- K-loop: 9 taps, A double-buffered one ahead, barrier per tap
    // (R7-proven: barrier separates all reads of a buffer from its rewrite).
#pragma unroll
    for (int t = 0; t < 9; t++) {
        const int kh = t / 3, kw = t - kh * 3;
        if (t + 1 < 9) { // issue tap t+1 into the other buffer
            const char* srcA = (const char*)wt + (size_t)(t + 1) * 16384;
            char* dstA = (char*)As + ((t + 1) & 1) * 16384;
#pragma unroll
            for (int i = 0; i < 2; i++) {
                const int c = wid * 2 + i;
                async16(srcA + c * 1024 + swl, dstA + c * 1024 + lane * 16);
            }
        }
        const short* At = As + (t & 1) * 8192; // shorts
#pragma unroll
        for (int kk = 0; kk < 2; kk++) {
            bf16x8 aa[4], bb[2];
#pragma unroll
            for (int mi = 0; mi < 4; mi++) {
                const int r = co0 + mi * 16 + col;
                aa[mi] = *(const bf16x8*)&At[(r * 64 + kk * 32 + quad * 8) ^ ((r & 7) << 3)];
            }
#pragma unroll
            for (int ni = 0; ni < 2; ni++) {
                const int r = (ohq + kh) * 68 + ow0 + ni * 16 + col + kw;
                bb[ni] = *(const bf16x8*)&halo[(r * 64 + kk * 32 + quad * 8) ^ ((r & 7) << 3)];
            }
#pragma unroll
            for (int mi = 0; mi < 4; mi++)
#pragma unroll
                for (int ni = 0; ni < 2; ni++)
                    acc[mi][ni] = __builtin_amdgcn_mfma_f32_16x16x32_bf16(
                        aa[mi], bb[ni], acc[mi][ni], 0, 0, 0);
        }
        if (t + 1 < 9) __syncthreads(); // tap t+1 DMA drained; buffer handoff
    }

    // ---- Epilogue: direct stores (proven time-neutral pattern). ----
    // C/D layout: col(N=spatial)=lane&15, row(M=co)=quad*4+reg.
    const int oh = oh0 + ohq; // always <= 125
#pragma unroll
    for (int ni = 0; ni < 2; ni++) {
        const int ow = W0 + ow0 + ni * 16 + col;
        if (ow < WO) {
#pragma unroll
            for (int mi = 0; mi < 4; mi++) {
                const int co = co0 + mi * 16 + quad * 4;
                float* o = out + (((size_t)b * COUT + co) * HO + oh) * WO + ow;
#pragma unroll
                for (int r = 0; r < 4; r++)
                    o[(size_t)r * HO * WO] = acc[mi][ni][r];
            }
        }
    }
}

// ---------- Fallback: direct fp32 conv (if d_ws too small) ----------
__global__ __launch_bounds__(256) void conv_direct(
        const float* __restrict__ x, const float* __restrict__ w,
        float* __restrict__ y) {
    const int idx = blockIdx.x * 256 + threadIdx.x;
    if (idx >= BATCH * COUT * HO * WO) return;
    const int ow = idx % WO;
    int t = idx / WO;
    const int oh = t % HO; t /= HO;
    const int co = t % COUT;
    const int b  = t / COUT;
    float acc = 0.f;
    const float* xb = x + (((size_t)b * CIN) * HIN + oh) * WIN + ow;
    const float* wc = w + (size_t)co * (CIN * 9);
    for (int ci = 0; ci < CIN; ci++) {
#pragma unroll
        for (int kh = 0; kh < 3; kh++)
#pragma unroll
            for (int kw = 0; kw < 3; kw++)
                acc += xb[(size_t)ci * (HIN * WIN) + kh * WIN + kw] * wc[ci * 9 + kh * 3 + kw];
    }
    y[idx] = acc;
}

extern "C" void kernel_launch(void* const* d_in, const int* in_sizes, int n_in,
                              void* d_out, int out_size, void* d_ws, size_t ws_size,
                              hipStream_t stream) {
    const float* data    = (const float*)d_in[0];
    const float* weights = (const float*)d_in[1];
    float* out = (float*)d_out;

    const size_t wt_bytes = (size_t)9 * COUT * CIN * 2; // 144 KiB

    if (ws_size >= wt_bytes) {
        unsigned short* wt = (unsigned short*)d_ws;
        t2_weights<<<(COUT * CIN * 9 + 255) / 256, 256, 0, stream>>>(weights, wt);
        conv_fused<<<dim3(2, 63, BATCH), 512, 0, stream>>>(data, wt, out);
    } else {
        const int n = BATCH * COUT * HO * WO;
        conv_direct<<<(n + 255) / 256, 256, 0, stream>>>(data, weights, out);
    }
}